// Round 2
// 1869.360 us; speedup vs baseline: 1.0098x; 1.0098x over previous
//
#include <hip/hip_runtime.h>

#define NN 50000
#define NE 400000
#define NT 300000
#define NQ 200000
#define DM 256
#define FIN 128
#define NRBF 40
#define BETA_RBF 40.0f
#define TOTALP 397569

// pass1 batch decomposition: 64 edges per batch
#define NB1 6250                 // NE/64 exactly
#define NB2 4688                 // ceil(NT/64), last batch has 32
#define NB3 3125                 // NQ/64 exactly
#define NBTOT (NB1 + NB2 + NB3)  // 14063

typedef unsigned int u32;
typedef unsigned short u16;

// ---- bf16 helpers ----
static __device__ __forceinline__ float bf2f(u16 h) {
  return __uint_as_float(((u32)h) << 16);
}
static __device__ __forceinline__ u16 f2bf(float f) {
  u32 u = __float_as_uint(f);
  u32 r = (u + 0x7FFFu + ((u >> 16) & 1u)) >> 16;  // RNE
  return (u16)r;
}
static __device__ __forceinline__ float4 ld4bf(const u16* p) {
  ushort4 v = *reinterpret_cast<const ushort4*>(p);
  return float4{bf2f(v.x), bf2f(v.y), bf2f(v.z), bf2f(v.w)};
}
static __device__ __forceinline__ float4 ld4f(const float* p) {
  return *reinterpret_cast<const float4*>(p);
}
static __device__ __forceinline__ float ldsc(const void* p, int isf, size_t i) {
  return isf ? ((const float*)p)[i] : bf2f(((const u16*)p)[i]);
}
static __device__ __forceinline__ float lk(float t) { return t >= 0.f ? t : 0.2f * t; }
static __device__ __forceinline__ u32 f2o(float f) {
  u32 u = __float_as_uint(f);
  return (u & 0x80000000u) ? ~u : (u | 0x80000000u);
}
static __device__ __forceinline__ float o2f(u32 e) {
  u32 b = (e & 0x80000000u) ? (e & 0x7fffffffu) : ~e;
  return __uint_as_float(b);
}

struct F3 { float x, y, z; };
static __device__ __forceinline__ F3 ldp(const float* pos, int i) {
  return F3{pos[3 * i], pos[3 * i + 1], pos[3 * i + 2]};
}
static __device__ __forceinline__ F3 sub3(F3 a, F3 b) { return F3{a.x - b.x, a.y - b.y, a.z - b.z}; }
static __device__ __forceinline__ float dot3(F3 a, F3 b) { return a.x * b.x + a.y * b.y + a.z * b.z; }
static __device__ __forceinline__ F3 cross3(F3 a, F3 b) {
  return F3{a.y * b.z - a.z * b.y, a.z * b.x - a.x * b.z, a.x * b.y - a.y * b.x};
}
static __device__ __forceinline__ float norm3(F3 v) { return sqrtf(dot3(v, v) + 1e-12f); }
static __device__ __forceinline__ float angle_at(F3 a, F3 m, F3 b) {
  F3 u = sub3(a, m), v = sub3(b, m);
  float c = dot3(u, v) / (norm3(u) * norm3(v) + 1e-12f);
  c = fminf(fmaxf(c, -1.f + 1e-7f), 1.f - 1e-7f);
  return acosf(c);
}
static __device__ __forceinline__ float dihedral_f(F3 p0, F3 p1, F3 p2, F3 p3) {
  F3 b1 = sub3(p1, p0), b2 = sub3(p2, p1), b3 = sub3(p3, p2);
  F3 n1 = cross3(b1, b2), n2 = cross3(b2, b3);
  float nb2 = norm3(b2) + 1e-12f;
  F3 b2n{b2.x / nb2, b2.y / nb2, b2.z / nb2};
  F3 m1 = cross3(n1, b2n);
  return atan2f(dot3(m1, n2), dot3(n1, n2) + 1e-12f);
}

// phase A: scalar RBF window + 8 coefficients for ONE edge (per lane).
// exp(-40(d-c)^2) < 4e-18 outside |d-c|>=1.0 -> 8-term window.
static __device__ __forceinline__ int rbf_coef(float d, float* c) {
  int j = (int)floorf(d * 4.0f) - 3;
  j = (j < 0) ? 0 : ((j > NRBF - 8) ? (NRBF - 8) : j);
  float t0 = d - 0.25f * (float)j;
#pragma unroll
  for (int k = 0; k < 8; ++k) {
    float t = t0 - 0.25f * (float)k;
    c[k] = __expf(-BETA_RBF * t * t);
  }
  return j;
}

// phase B: dm += sum_k c_k * Wu[j+k][c4..c4+3]  (k ascending, same order as before)
static __device__ __forceinline__ float4 rbf_apply(const float* __restrict__ base,
                                                   float4 c0, float4 c1, float4 dm) {
  float4 w;
  w = ld4f(base + 0 * DM);
  dm.x = fmaf(c0.x, w.x, dm.x); dm.y = fmaf(c0.x, w.y, dm.y);
  dm.z = fmaf(c0.x, w.z, dm.z); dm.w = fmaf(c0.x, w.w, dm.w);
  w = ld4f(base + 1 * DM);
  dm.x = fmaf(c0.y, w.x, dm.x); dm.y = fmaf(c0.y, w.y, dm.y);
  dm.z = fmaf(c0.y, w.z, dm.z); dm.w = fmaf(c0.y, w.w, dm.w);
  w = ld4f(base + 2 * DM);
  dm.x = fmaf(c0.z, w.x, dm.x); dm.y = fmaf(c0.z, w.y, dm.y);
  dm.z = fmaf(c0.z, w.z, dm.z); dm.w = fmaf(c0.z, w.w, dm.w);
  w = ld4f(base + 3 * DM);
  dm.x = fmaf(c0.w, w.x, dm.x); dm.y = fmaf(c0.w, w.y, dm.y);
  dm.z = fmaf(c0.w, w.z, dm.z); dm.w = fmaf(c0.w, w.w, dm.w);
  w = ld4f(base + 4 * DM);
  dm.x = fmaf(c1.x, w.x, dm.x); dm.y = fmaf(c1.x, w.y, dm.y);
  dm.z = fmaf(c1.x, w.z, dm.z); dm.w = fmaf(c1.x, w.w, dm.w);
  w = ld4f(base + 5 * DM);
  dm.x = fmaf(c1.y, w.x, dm.x); dm.y = fmaf(c1.y, w.y, dm.y);
  dm.z = fmaf(c1.y, w.z, dm.z); dm.w = fmaf(c1.y, w.w, dm.w);
  w = ld4f(base + 6 * DM);
  dm.x = fmaf(c1.z, w.x, dm.x); dm.y = fmaf(c1.z, w.y, dm.y);
  dm.z = fmaf(c1.z, w.z, dm.z); dm.w = fmaf(c1.z, w.w, dm.w);
  w = ld4f(base + 7 * DM);
  dm.x = fmaf(c1.w, w.x, dm.x); dm.y = fmaf(c1.w, w.y, dm.y);
  dm.z = fmaf(c1.w, w.z, dm.z); dm.w = fmaf(c1.w, w.w, dm.w);
  return dm;
}

static __device__ __forceinline__ ushort4 g512(const u16* p, int idx, int c4) {
  return *reinterpret_cast<const ushort4*>(p + (size_t)(u32)idx * DM + c4);
}
static __device__ __forceinline__ float4 cvt4(ushort4 v) {
  return float4{bf2f(v.x), bf2f(v.y), bf2f(v.z), bf2f(v.w)};
}

// param staging table: 30 tensors, cumulative offsets
__device__ const int g_off[31] = {
  0, 32768, 65536, 98304, 131072, 131584, 131840, 142080, 142336, 152576,
  152832, 163072, 163328, 163840, 164096, 165632, 165888, 231424, 231680,
  297216, 297472, 363008, 363264, 363520, 363776, 364032, 396800, 397056,
  397312, 397568, 397569};
struct PtrTab { const void* p[30]; };

// ---- init ----
__global__ __launch_bounds__(256) void init_detect(const u32* __restrict__ aw,
                                                   const u32* __restrict__ lng,
                                                   u32* __restrict__ gmax,
                                                   int* __restrict__ flags) {
  __shared__ int s_int, s_f32, s_bf;
  if (threadIdx.x == 0) { s_int = 1; s_f32 = 1; s_bf = 1; }
  __syncthreads();
  int li = 1, lf = 1, lb = 1;
  for (int i = threadIdx.x; i < 1024; i += 256) {
    u32 w = aw[i];
    if (w > 1u) li = 0;
    if (w != 0u && w != 0x3F800000u) lf = 0;
    u32 h0 = w & 0xFFFFu, h1 = w >> 16;
    if ((h0 != 0u && h0 != 0x3F80u) || (h1 != 0u && h1 != 0x3F80u)) lb = 0;
  }
  if (!li) atomicAnd(&s_int, 0);
  if (!lf) atomicAnd(&s_f32, 0);
  if (!lb) atomicAnd(&s_bf, 0);
  __syncthreads();
  if (threadIdx.x == 0) {
    flags[0] = s_int ? 0 : (s_f32 ? 2 : (s_bf ? 3 : 1));
    flags[1] = ((lng[0] & 0xFFFFu) == 0x3F80u) ? 0 : 1;  // 1 = fp32 inputs
    gmax[0] = f2o(-INFINITY);
    gmax[1] = f2o(-INFINITY);
    gmax[2] = f2o(-INFINITY);
    gmax[3] = 0u;  // pass1 work-steal counter
  }
}

__global__ __launch_bounds__(256) void convert_params(PtrTab tab,
                                                      const int* __restrict__ flags,
                                                      float* __restrict__ dst) {
  const int isf = flags[1];
  for (int i = blockIdx.x * blockDim.x + threadIdx.x; i < TOTALP;
       i += gridDim.x * blockDim.x) {
    int t = 0;
    while (i >= g_off[t + 1]) ++t;
    dst[i] = ldsc(tab.p[t], isf, i - g_off[t]);
  }
}
__global__ __launch_bounds__(256) void convert_pos(const void* __restrict__ pos,
                                                   const int* __restrict__ flags,
                                                   float* __restrict__ posf) {
  const int isf = flags[1];
  for (int i = blockIdx.x * blockDim.x + threadIdx.x; i < NN * 3;
       i += gridDim.x * blockDim.x)
    posf[i] = ldsc(pos, isf, i);
}

static __device__ __forceinline__ int read_eattr(const void* p, int flag, int e) {
  if (flag == 1) return ((const unsigned char*)p)[e];
  if (flag == 2) return (((const float*)p)[e] != 0.f);
  if (flag == 3) return (((const u16*)p)[e] != 0);
  return ((const int*)p)[e];
}

// ---- fused 4-way projection ----
__global__ __launch_bounds__(256) void proj4_kernel(
    const void* __restrict__ x, const int* __restrict__ flags,
    const float* __restrict__ W0, const float* __restrict__ W1,
    const float* __restrict__ W2, const float* __restrict__ W3,
    u16* __restrict__ o0, u16* __restrict__ o1,
    u16* __restrict__ o2, u16* __restrict__ o3) {
  __shared__ float sx[16 * FIN];
  const int c = threadIdx.x;
  const int n0 = blockIdx.x * 16;
  const int isf = flags[1];
#pragma unroll
  for (int i = 0; i < 8; ++i) {
    int l = i * 256 + c;
    sx[l] = ldsc(x, isf, (size_t)n0 * FIN + l);
  }
  __syncthreads();
  float dv = expf(-logf(10000.f) * (float)(c & ~1) / 256.f);
  float p0 = (c & 1) ? cosf(0.f * dv) : sinf(0.f * dv);
  float p1 = (c & 1) ? cosf(1.f * dv) : sinf(1.f * dv);
  float p2 = (c & 1) ? cosf(2.f * dv) : sinf(2.f * dv);
  float p3 = (c & 1) ? cosf(3.f * dv) : sinf(3.f * dv);
  float a0[16], a1[16], a2[16], a3[16];
#pragma unroll
  for (int r = 0; r < 16; ++r) { a0[r] = p0; a1[r] = p1; a2[r] = p2; a3[r] = p3; }
  for (int k = 0; k < FIN; ++k) {
    float w0 = W0[k * DM + c], w1 = W1[k * DM + c];
    float w2 = W2[k * DM + c], w3 = W3[k * DM + c];
#pragma unroll
    for (int r = 0; r < 16; ++r) {
      float xr = sx[r * FIN + k];
      a0[r] = fmaf(xr, w0, a0[r]);
      a1[r] = fmaf(xr, w1, a1[r]);
      a2[r] = fmaf(xr, w2, a2[r]);
      a3[r] = fmaf(xr, w3, a3[r]);
    }
  }
#pragma unroll
  for (int r = 0; r < 16; ++r) {
    size_t off = (size_t)(n0 + r) * DM + c;
    o0[off] = f2bf(a0[r]); o1[off] = f2bf(a1[r]);
    o2[off] = f2bf(a2[r]); o3[off] = f2bf(a3[r]);
  }
}

// ---- fused CSR build over the 3 hops ----
__global__ __launch_bounds__(256) void hist_all(const int* __restrict__ ed,
                                                const int* __restrict__ td,
                                                const int* __restrict__ qd,
                                                int* __restrict__ deg) {
  const int M = NE + NT + NQ;
  for (int i = blockIdx.x * blockDim.x + threadIdx.x; i < M; i += gridDim.x * blockDim.x) {
    if (i < NE) atomicAdd(&deg[ed[i]], 1);
    else if (i < NE + NT) atomicAdd(&deg[NN + td[i - NE]], 1);
    else atomicAdd(&deg[2 * NN + qd[i - NE - NT]], 1);
  }
}
__global__ __launch_bounds__(1024) void scan_all(const int* __restrict__ degall,
                                                 int* __restrict__ offall,
                                                 int* __restrict__ curall) {
  __shared__ int part[1024];
  const int b = blockIdx.x;
  const int* deg = degall + (size_t)b * NN;
  int* off = offall + (size_t)b * (NN + 1);
  int* cur = curall + (size_t)b * NN;
  const int CH = (NN + 1023) / 1024;
  const int t = threadIdx.x;
  const int base = t * CH;
  int s = 0;
  for (int i = 0; i < CH; ++i) { int idx = base + i; if (idx < NN) s += deg[idx]; }
  part[t] = s;
  __syncthreads();
  for (int d = 1; d < 1024; d <<= 1) {
    int v = (t >= d) ? part[t - d] : 0;
    __syncthreads();
    part[t] += v;
    __syncthreads();
  }
  int run = (t == 0) ? 0 : part[t - 1];
  for (int i = 0; i < CH; ++i) {
    int idx = base + i;
    if (idx < NN) { off[idx] = run; cur[idx] = run; run += deg[idx]; }
  }
  if (t == 1023) off[NN] = run;
}
__global__ __launch_bounds__(256) void fill_all(const int* __restrict__ ed,
                                                const int* __restrict__ td,
                                                const int* __restrict__ qd,
                                                int* __restrict__ cur,
                                                int* __restrict__ eid) {
  const int M = NE + NT + NQ;
  for (int i = blockIdx.x * blockDim.x + threadIdx.x; i < M; i += gridDim.x * blockDim.x) {
    if (i < NE) {
      int p = atomicAdd(&cur[ed[i]], 1);
      eid[p] = i;
    } else if (i < NE + NT) {
      int il = i - NE;
      int p = atomicAdd(&cur[NN + td[il]], 1);
      eid[NE + p] = il;
    } else {
      int il = i - NE - NT;
      int p = atomicAdd(&cur[2 * NN + qd[il]], 1);
      eid[NE + NT + p] = il;
    }
  }
}

// ---- fused pass1, restructured ----
// Per-wave batches of 64 edges, dynamically stolen via gmax[3].
// Phase A (edge-per-lane): geometry + RBF coefficients computed ONCE per edge,
//   staged in a private per-wave LDS slab (64 edges x 20 words = 5 KB/wave).
// Phase B (channel-per-lane): per-edge channel math with wave-uniform LDS
//   broadcast of the staged scalars; next edge's struct + feature gathers
//   prefetched one iteration ahead.
__global__ __launch_bounds__(256, 4) void pass1_all(
    const float* __restrict__ pos,
    const int* __restrict__ eidx, const int* __restrict__ tdx, const int* __restrict__ qdx,
    const void* __restrict__ eattr, const int* __restrict__ flags,
    const u16* __restrict__ p_src, const u16* __restrict__ p_mid2,
    const u16* __restrict__ p_mid1, const u16* __restrict__ p_dst,
    const float* __restrict__ fp,
    float* __restrict__ score1, float* __restrict__ score2, float* __restrict__ score3,
    u32* __restrict__ gmax) {
  __shared__ __align__(16) float slds[4][64 * 20];
  const int lane = threadIdx.x & 63;
  float* sw = slds[threadIdx.x >> 6];
  const int c4 = lane * 4;
  const int flag = flags[0];

  // bounded loop: guaranteed termination even if the counter were corrupted
  for (int it = 0; it <= NBTOT; ++it) {
    u32 bl = 0;
    if (lane == 0) bl = atomicAdd(gmax + 3, 1u);
    u32 b0 = (u32)__builtin_amdgcn_readfirstlane((int)bl);
    if (b0 >= NBTOT) break;

    if (b0 < NB1) {
      // ================= hop 1 =================
      const int e0 = (int)b0 * 64;
      {  // phase A
        int e = e0 + lane;
        int es = eidx[e], ed = eidx[NE + e];
        int ea = read_eattr(eattr, flag, e);
        F3 Ps = ldp(pos, es), Pd = ldp(pos, ed);
        float d1 = norm3(sub3(Ps, Pd));
        float c[8]; int j = 0; float f0, f1;
        if (ea) {
          float dc = fminf(fmaxf(d1, 0.05f), 10.f);
          j = rbf_coef(dc, c);
          f0 = 0.f; f1 = 0.f;
        } else {
#pragma unroll
          for (int k = 0; k < 8; ++k) c[k] = 0.f;
          f0 = d1; f1 = d1 * d1;
        }
        float* sp = sw + lane * 20;
        *reinterpret_cast<int4*>(sp) = int4{es, ed, ea, j};
        *reinterpret_cast<float4*>(sp + 4) = float4{c[0], c[1], c[2], c[3]};
        *reinterpret_cast<float4*>(sp + 8) = float4{c[4], c[5], c[6], c[7]};
        *reinterpret_cast<float4*>(sp + 12) = float4{f0, f1, 0.f, 0.f};
      }
      // phase B
      const float* Wu = fp + 131840;
      float4 av = ld4f(fp + 363264 + c4);
      float4 bbv = ld4f(fp + 131584 + c4), buv = ld4f(fp + 142080 + c4);
      float4 bsum{bbv.x + buv.x, bbv.y + buv.y, bbv.z + buv.z, bbv.w + buv.w};
      float4 wb0 = ld4f(fp + 131072 + c4), wb1 = ld4f(fp + 131072 + DM + c4);
      float rmax = -INFINITY;
      int4 I = *reinterpret_cast<const int4*>(sw);
      ushort4 gm = g512(p_mid1, I.x, c4);
      ushort4 gd = g512(p_dst, I.y, c4);
#pragma unroll 1
      for (int e = 0; e < 64; ++e) {
        int4 In{0, 0, 0, 0};
        ushort4 gmn{0, 0, 0, 0}, gdn{0, 0, 0, 0};
        if (e + 1 < 64) {
          In = *reinterpret_cast<const int4*>(sw + (e + 1) * 20);
          gmn = g512(p_mid1, In.x, c4);
          gdn = g512(p_dst, In.y, c4);
        }
        const float* sp = sw + e * 20;
        float4 dm = bsum;
        if (I.z) {
          float4 cc0 = *reinterpret_cast<const float4*>(sp + 4);
          float4 cc1 = *reinterpret_cast<const float4*>(sp + 8);
          dm = rbf_apply(Wu + I.w * DM + c4, cc0, cc1, dm);
        } else {
          float4 f = *reinterpret_cast<const float4*>(sp + 12);
          dm.x = fmaf(f.x, wb0.x, fmaf(f.y, wb1.x, dm.x));
          dm.y = fmaf(f.x, wb0.y, fmaf(f.y, wb1.y, dm.y));
          dm.z = fmaf(f.x, wb0.z, fmaf(f.y, wb1.z, dm.z));
          dm.w = fmaf(f.x, wb0.w, fmaf(f.y, wb1.w, dm.w));
        }
        float4 m = cvt4(gm), dd = cvt4(gd);
        float s0 = lk((m.x + dd.x) * dm.x);
        float s1 = lk((m.y + dd.y) * dm.y);
        float s2 = lk((m.z + dd.z) * dm.z);
        float s3 = lk((m.w + dd.w) * dm.w);
        float part = av.x * s0 + av.y * s1 + av.z * s2 + av.w * s3;
        part += __shfl_xor(part, 1, 64);
        part += __shfl_xor(part, 2, 64);
        part += __shfl_xor(part, 4, 64);
        if ((lane & 7) == 0) score1[(size_t)(e0 + e) * 8 + (lane >> 3)] = part;
        rmax = fmaxf(rmax, part);
        I = In; gm = gmn; gd = gdn;
      }
      for (int m = 32; m; m >>= 1) rmax = fmaxf(rmax, __shfl_xor(rmax, m, 64));
      if (lane == 0) atomicMax(gmax + 0, f2o(rmax));
    } else if (b0 < NB1 + NB2) {
      // ================= hop 2 =================
      const int t0 = ((int)b0 - NB1) * 64;
      const int cnt = (NT - t0 < 64) ? (NT - t0) : 64;
      if (lane < cnt) {  // phase A
        int t = t0 + lane;
        int ts = tdx[t], tm = tdx[NT + t], td = tdx[2 * NT + t];
        F3 Ps = ldp(pos, ts), Pm = ldp(pos, tm), Pd = ldp(pos, td);
        float d2 = fminf(fmaxf(norm3(sub3(Ps, Pd)), 0.05f), 10.f);
        float c[8];
        int j = rbf_coef(d2, c);
        float ang = angle_at(Ps, Pm, Pd);
        float* sp = sw + lane * 20;
        *reinterpret_cast<int4*>(sp) = int4{ts, tm, td, j};
        *reinterpret_cast<float4*>(sp + 4) = float4{c[0], c[1], c[2], c[3]};
        *reinterpret_cast<float4*>(sp + 8) = float4{c[4], c[5], c[6], c[7]};
        *reinterpret_cast<float4*>(sp + 12) = float4{ang, ang * ang, 0.f, 0.f};
      }
      // phase B
      const float* Wu1 = fp + 142336;
      float4 av = ld4f(fp + 363520 + c4);
      float4 b1v = ld4f(fp + 152576 + c4), b2v = ld4f(fp + 163840 + c4);
      float4 bsum{b1v.x + b2v.x, b1v.y + b2v.y, b1v.z + b2v.z, b1v.w + b2v.w};
      float4 wa0 = ld4f(fp + 163328 + c4), wa1 = ld4f(fp + 163328 + DM + c4);
      float rmax = -INFINITY;
      int4 I = *reinterpret_cast<const int4*>(sw);
      ushort4 g0 = g512(p_mid2, I.x, c4);
      ushort4 g1 = g512(p_mid1, I.y, c4);
      ushort4 g2 = g512(p_dst, I.z, c4);
#pragma unroll 1
      for (int e = 0; e < cnt; ++e) {
        int4 In{0, 0, 0, 0};
        ushort4 g0n{0, 0, 0, 0}, g1n{0, 0, 0, 0}, g2n{0, 0, 0, 0};
        if (e + 1 < cnt) {
          In = *reinterpret_cast<const int4*>(sw + (e + 1) * 20);
          g0n = g512(p_mid2, In.x, c4);
          g1n = g512(p_mid1, In.y, c4);
          g2n = g512(p_dst, In.z, c4);
        }
        const float* sp = sw + e * 20;
        float4 cc0 = *reinterpret_cast<const float4*>(sp + 4);
        float4 cc1 = *reinterpret_cast<const float4*>(sp + 8);
        float4 f = *reinterpret_cast<const float4*>(sp + 12);
        float4 dm;
        dm.x = fmaf(f.x, wa0.x, fmaf(f.y, wa1.x, bsum.x));
        dm.y = fmaf(f.x, wa0.y, fmaf(f.y, wa1.y, bsum.y));
        dm.z = fmaf(f.x, wa0.z, fmaf(f.y, wa1.z, bsum.z));
        dm.w = fmaf(f.x, wa0.w, fmaf(f.y, wa1.w, bsum.w));
        dm = rbf_apply(Wu1 + I.w * DM + c4, cc0, cc1, dm);
        float4 v0 = cvt4(g0), v2 = cvt4(g1), v1 = cvt4(g2);
        float s0 = lk((v0.x + v1.x + v2.x) * dm.x);
        float s1 = lk((v0.y + v1.y + v2.y) * dm.y);
        float s2 = lk((v0.z + v1.z + v2.z) * dm.z);
        float s3 = lk((v0.w + v1.w + v2.w) * dm.w);
        float part = av.x * s0 + av.y * s1 + av.z * s2 + av.w * s3;
        part += __shfl_xor(part, 1, 64);
        part += __shfl_xor(part, 2, 64);
        part += __shfl_xor(part, 4, 64);
        if ((lane & 7) == 0) score2[(size_t)(t0 + e) * 8 + (lane >> 3)] = part;
        rmax = fmaxf(rmax, part);
        I = In; g0 = g0n; g1 = g1n; g2 = g2n;
      }
      for (int m = 32; m; m >>= 1) rmax = fmaxf(rmax, __shfl_xor(rmax, m, 64));
      if (lane == 0) atomicMax(gmax + 1, f2o(rmax));
    } else {
      // ================= hop 3 =================
      const int q0 = ((int)b0 - NB1 - NB2) * 64;
      {  // phase A
        int q = q0 + lane;
        int qs = qdx[q], q2 = qdx[NQ + q], q1 = qdx[2 * NQ + q], qd = qdx[3 * NQ + q];
        F3 P0 = ldp(pos, qs), P1 = ldp(pos, q2), P2 = ldp(pos, q1), P3 = ldp(pos, qd);
        float d3 = fminf(fmaxf(norm3(sub3(P0, P3)), 0.05f), 10.f);
        float c[8];
        int j = rbf_coef(d3, c);
        float a1f = angle_at(P0, P1, P2);
        float a2f = angle_at(P1, P2, P3);
        float dh = dihedral_f(P0, P1, P2, P3);
        float* sp = sw + lane * 20;
        *reinterpret_cast<int4*>(sp) = int4{qs, q2, q1, qd};
        *reinterpret_cast<float4*>(sp + 4) = float4{c[0], c[1], c[2], c[3]};
        *reinterpret_cast<float4*>(sp + 8) = float4{c[4], c[5], c[6], c[7]};
        *reinterpret_cast<float4*>(sp + 12) = float4{a1f, a1f * a1f, a2f, a2f * a2f};
        *reinterpret_cast<float4*>(sp + 16) = float4{dh, dh * dh, __int_as_float(j), 0.f};
      }
      // phase B
      const float* Wu2 = fp + 152832;
      const float* Wd = fp + 164096;
      float4 av = ld4f(fp + 363776 + c4);
      float4 b1v = ld4f(fp + 163072 + c4), b2v = ld4f(fp + 165632 + c4);
      float4 bsum{b1v.x + b2v.x, b1v.y + b2v.y, b1v.z + b2v.z, b1v.w + b2v.w};
      float4 wd0 = ld4f(Wd + c4), wd1 = ld4f(Wd + DM + c4), wd2 = ld4f(Wd + 2 * DM + c4);
      float4 wd3 = ld4f(Wd + 3 * DM + c4), wd4 = ld4f(Wd + 4 * DM + c4), wd5 = ld4f(Wd + 5 * DM + c4);
      float rmax = -INFINITY;
      int4 I = *reinterpret_cast<const int4*>(sw);
      float4 fb = *reinterpret_cast<const float4*>(sw + 16);
      ushort4 g0 = g512(p_src, I.x, c4), g1 = g512(p_mid2, I.y, c4);
      ushort4 g2 = g512(p_mid1, I.z, c4), g3 = g512(p_dst, I.w, c4);
#pragma unroll 1
      for (int e = 0; e < 64; ++e) {
        int4 In{0, 0, 0, 0};
        float4 fbn{0.f, 0.f, 0.f, 0.f};
        ushort4 g0n{0, 0, 0, 0}, g1n{0, 0, 0, 0}, g2n{0, 0, 0, 0}, g3n{0, 0, 0, 0};
        if (e + 1 < 64) {
          In = *reinterpret_cast<const int4*>(sw + (e + 1) * 20);
          fbn = *reinterpret_cast<const float4*>(sw + (e + 1) * 20 + 16);
          g0n = g512(p_src, In.x, c4);
          g1n = g512(p_mid2, In.y, c4);
          g2n = g512(p_mid1, In.z, c4);
          g3n = g512(p_dst, In.w, c4);
        }
        const float* sp = sw + e * 20;
        float4 cc0 = *reinterpret_cast<const float4*>(sp + 4);
        float4 cc1 = *reinterpret_cast<const float4*>(sp + 8);
        float4 f = *reinterpret_cast<const float4*>(sp + 12);
        int j = __float_as_int(fb.z);
        float4 dm;
        dm.x = bsum.x + f.x * wd0.x + f.y * wd1.x + f.z * wd2.x + f.w * wd3.x + fb.x * wd4.x + fb.y * wd5.x;
        dm.y = bsum.y + f.x * wd0.y + f.y * wd1.y + f.z * wd2.y + f.w * wd3.y + fb.x * wd4.y + fb.y * wd5.y;
        dm.z = bsum.z + f.x * wd0.z + f.y * wd1.z + f.z * wd2.z + f.w * wd3.z + fb.x * wd4.z + fb.y * wd5.z;
        dm.w = bsum.w + f.x * wd0.w + f.y * wd1.w + f.z * wd2.w + f.w * wd3.w + fb.x * wd4.w + fb.y * wd5.w;
        dm = rbf_apply(Wu2 + j * DM + c4, cc0, cc1, dm);
        float4 v0 = cvt4(g0), v1 = cvt4(g1), v2 = cvt4(g2), v3 = cvt4(g3);
        float s0 = lk((v0.x + v1.x + v2.x + v3.x) * dm.x);
        float s1 = lk((v0.y + v1.y + v2.y + v3.y) * dm.y);
        float s2 = lk((v0.z + v1.z + v2.z + v3.z) * dm.z);
        float s3 = lk((v0.w + v1.w + v2.w + v3.w) * dm.w);
        float part = av.x * s0 + av.y * s1 + av.z * s2 + av.w * s3;
        part += __shfl_xor(part, 1, 64);
        part += __shfl_xor(part, 2, 64);
        part += __shfl_xor(part, 4, 64);
        if ((lane & 7) == 0) score3[(size_t)(q0 + e) * 8 + (lane >> 3)] = part;
        rmax = fmaxf(rmax, part);
        I = In; fb = fbn; g0 = g0n; g1 = g1n; g2 = g2n; g3 = g3n;
      }
      for (int m = 32; m; m >>= 1) rmax = fmaxf(rmax, __shfl_xor(rmax, m, 64));
      if (lane == 0) atomicMax(gmax + 2, f2o(rmax));
    }
  }
}

// ---- fused gather: 3*NN waves, writes bf16 out1/out2/out3 ----
__global__ __launch_bounds__(256) void gather_all(
    const u16* __restrict__ p_src, const u16* __restrict__ p_mid2,
    const u16* __restrict__ p_mid1,
    const int* __restrict__ eidx, const int* __restrict__ tdx, const int* __restrict__ qdx,
    const float* __restrict__ score1, const float* __restrict__ score2,
    const float* __restrict__ score3,
    const int* __restrict__ offall, const int* __restrict__ eidall,
    const u32* __restrict__ gmax,
    u16* __restrict__ out1, u16* __restrict__ out2, u16* __restrict__ out3) {
  const int W = (blockIdx.x * blockDim.x + threadIdx.x) >> 6;
  if (W >= 3 * NN) return;
  const int lane = threadIdx.x & 63;
  const int h = lane >> 3;
  const int c4 = lane * 4;
  const int hop = (W < NN) ? 0 : ((W < 2 * NN) ? 1 : 2);
  const int node = W - hop * NN;
  const int* offp = offall + (size_t)hop * (NN + 1);
  const int* eidp = eidall + ((hop == 0) ? 0 : ((hop == 1) ? NE : (NE + NT)));
  const int* gsrc = (hop == 0) ? eidx : ((hop == 1) ? tdx : qdx);
  const float* scr = (hop == 0) ? score1 : ((hop == 1) ? score2 : score3);
  const u16* sv = (hop == 0) ? p_mid1 : ((hop == 1) ? p_mid2 : p_src);
  u16* outp = (hop == 0) ? out1 : ((hop == 1) ? out2 : out3);
  const float g = o2f(gmax[hop]);
  const int s0 = offp[node], s1 = offp[node + 1];
  float4 vacc{0.f, 0.f, 0.f, 0.f};
  float wsum = 0.f;
  for (int j = s0; j < s1; ++j) {
    int e = eidp[j];
    int s = gsrc[e];
    float ev = expf(scr[(size_t)e * 8 + h] - g);
    wsum += ev;
    float4 v = ld4bf(sv + (size_t)s * DM + c4);
    vacc.x = fmaf(ev, v.x, vacc.x);
    vacc.y = fmaf(ev, v.y, vacc.y);
    vacc.z = fmaf(ev, v.z, vacc.z);
    vacc.w = fmaf(ev, v.w, vacc.w);
  }
  float inv = 1.f / (wsum + 1e-16f);
  ushort4 o;
  o.x = f2bf(vacc.x * inv);
  o.y = f2bf(vacc.y * inv);
  o.z = f2bf(vacc.z * inv);
  o.w = f2bf(vacc.w * inv);
  *reinterpret_cast<ushort4*>(outp + (size_t)node * DM + c4) = o;
}

// ---- fused output GEMM (K=896) + LayerNorm + PReLU, single write of d_out ----
__global__ __launch_bounds__(256) void gemm_ln(
    const u16* __restrict__ out1, const u16* __restrict__ out2,
    const u16* __restrict__ out3, const void* __restrict__ x,
    const int* __restrict__ flags, const float* __restrict__ fp,
    float* __restrict__ outp) {
  __shared__ float smA[16 * 768];  // 48 KB: out1|out2|out3 per row
  __shared__ float smX[16 * FIN];  // 8 KB
  __shared__ float redS[4][16], redQ[4][16];
  const int c = threadIdx.x;
  const int n0 = blockIdx.x * 16;
  const int isf = flags[1];
  const float* W1 = fp + 165888;
  const float* W2 = fp + 231680;
  const float* W3 = fp + 297472;
  const float* Wr = fp + 364032;
  const float* b1 = fp + 231424;
  const float* b2 = fp + 297216;
  const float* b3 = fp + 363008;
  const float* bias = fp + 396800;
  const float* ln_g = fp + 397056;
  const float* ln_b = fp + 397312;
  const float* prelu = fp + 397568;

  for (int i = c; i < 16 * 256; i += 256) {
    int r = i >> 8, k = i & 255;
    size_t gi = (size_t)(n0 + r) * DM + k;
    smA[r * 768 + k] = bf2f(out1[gi]);
    smA[r * 768 + 256 + k] = bf2f(out2[gi]);
    smA[r * 768 + 512 + k] = bf2f(out3[gi]);
  }
  for (int i = c; i < 16 * FIN; i += 256) {
    int r = i >> 7, k = i & 127;
    smX[r * FIN + k] = ldsc(x, isf, (size_t)(n0 + r) * FIN + k);
  }
  __syncthreads();

  float acc[16];
  float base = b1[c] + b2[c] + b3[c] + bias[c];
#pragma unroll
  for (int r = 0; r < 16; ++r) acc[r] = base;

  const float* Ws[3] = {W1, W2, W3};
#pragma unroll 1
  for (int seg = 0; seg < 3; ++seg) {
    const float* W = Ws[seg];
    const float* A = smA + seg * 256;
    for (int k = 0; k < 256; k += 4) {
      float w0 = W[k * DM + c], w1 = W[(k + 1) * DM + c];
      float w2 = W[(k + 2) * DM + c], w3 = W[(k + 3) * DM + c];
#pragma unroll
      for (int r = 0; r < 16; ++r) {
        float4 a = *reinterpret_cast<const float4*>(&A[r * 768 + k]);
        acc[r] = fmaf(a.x, w0, acc[r]);
        acc[r] = fmaf(a.y, w1, acc[r]);
        acc[r] = fmaf(a.z, w2, acc[r]);
        acc[r] = fmaf(a.w, w3, acc[r]);
      }
    }
  }
  for (int k = 0; k < FIN; k += 4) {
    float w0 = Wr[k * DM + c], w1 = Wr[(k + 1) * DM + c];
    float w2 = Wr[(k + 2) * DM + c], w3 = Wr[(k + 3) * DM + c];
#pragma unroll
    for (int r = 0; r < 16; ++r) {
      float4 a = *reinterpret_cast<const float4*>(&smX[r * FIN + k]);
      acc[r] = fmaf(a.x, w0, acc[r]);
      acc[r] = fmaf(a.y, w1, acc[r]);
      acc[r] = fmaf(a.z, w2, acc[r]);
      acc[r] = fmaf(a.w, w3, acc[r]);
    }
  }

  // LayerNorm reduction across the 256 threads (= 256 channels) per row
  const int w = c >> 6, l = c & 63;
#pragma unroll
  for (int r = 0; r < 16; ++r) {
    float s = acc[r], q = acc[r] * acc[r];
    for (int m = 32; m; m >>= 1) {
      s += __shfl_xor(s, m, 64);
      q += __shfl_xor(q, m, 64);
    }
    if (l == 0) { redS[w][r] = s; redQ[w][r] = q; }
  }
  __syncthreads();
  float g = ln_g[c], bt = ln_b[c], pw = prelu[0];
#pragma unroll
  for (int r = 0; r < 16; ++r) {
    float S = redS[0][r] + redS[1][r] + redS[2][r] + redS[3][r];
    float Q = redQ[0][r] + redQ[1][r] + redQ[2][r] + redQ[3][r];
    float mu = S * (1.f / 256.f);
    float var = fmaxf(Q * (1.f / 256.f) - mu * mu, 0.f);
    float y = (acc[r] - mu) * rsqrtf(var + 1e-5f) * g + bt;
    outp[(size_t)(n0 + r) * DM + c] = (y >= 0.f) ? y : pw * y;
  }
}

extern "C" void kernel_launch(void* const* d_in, const int* in_sizes, int n_in,
                              void* d_out, int out_size, void* d_ws, size_t ws_size,
                              hipStream_t stream) {
  const void* x = d_in[0];
  const void* pos = d_in[1];
  const int* eidx = (const int*)d_in[2];
  const int* tdx = (const int*)d_in[3];
  const int* qdx = (const int*)d_in[4];
  const void* eattr = d_in[5];
  float* outp = (float*)d_out;

  // workspace layout (~216 MB; proven safe <= ~221 MB)
  u16* p_src = (u16*)d_ws;
  u16* p_mid2 = p_src + (size_t)NN * DM;
  u16* p_mid1 = p_mid2 + (size_t)NN * DM;
  u16* p_dst = p_mid1 + (size_t)NN * DM;
  u16* out1 = p_dst + (size_t)NN * DM;
  u16* out2 = out1 + (size_t)NN * DM;
  u16* out3 = out2 + (size_t)NN * DM;
  float* score1 = (float*)(out3 + (size_t)NN * DM);   // NE*8
  float* score2 = score1 + (size_t)NE * 8;            // NT*8
  float* score3 = score2 + (size_t)NT * 8;            // NQ*8
  float* posf = score3 + (size_t)NQ * 8;              // NN*3
  float* fp = posf + (size_t)NN * 3;                  // staged params
  int* deg = (int*)(fp + TOTALP + 3);                 // 3*NN
  int* off = deg + 3 * NN;                            // 3*(NN+1)
  int* cur = off + 3 * (NN + 1);                      // 3*NN
  int* eid = cur + 3 * NN;                            // NE+NT+NQ
  u32* gmax = (u32*)(eid + NE + NT + NQ);
  int* flags = (int*)(gmax + 4);

  const float* W_src = fp + 0;
  const float* W_dst = fp + 32768;
  const float* W_mid1 = fp + 65536;
  const float* W_mid2 = fp + 98304;

  init_detect<<<1, 256, 0, stream>>>((const u32*)eattr, (const u32*)d_in[33], gmax, flags);

  PtrTab tab;
  for (int i = 0; i < 30; ++i) tab.p[i] = d_in[6 + i];
  convert_params<<<512, 256, 0, stream>>>(tab, flags, fp);
  convert_pos<<<587, 256, 0, stream>>>(pos, flags, posf);

  proj4_kernel<<<NN / 16, 256, 0, stream>>>(x, flags, W_src, W_mid2, W_mid1, W_dst,
                                            p_src, p_mid2, p_mid1, p_dst);

  // CSR for all 3 hops
  hipMemsetAsync(deg, 0, (size_t)3 * NN * 4, stream);
  hist_all<<<1024, 256, 0, stream>>>(eidx + NE, tdx + 2 * NT, qdx + 3 * NQ, deg);
  scan_all<<<3, 1024, 0, stream>>>(deg, off, cur);
  fill_all<<<1024, 256, 0, stream>>>(eidx + NE, tdx + 2 * NT, qdx + 3 * NQ, cur, eid);

  // fused score pass (dynamic wave-level work stealing over 64-edge batches)
  pass1_all<<<2048, 256, 0, stream>>>(posf, eidx, tdx, qdx, eattr, flags,
                                      p_src, p_mid2, p_mid1, p_dst, fp,
                                      score1, score2, score3, gmax);

  // fused softmax-aggregate
  gather_all<<<(3 * NN + 3) / 4, 256, 0, stream>>>(p_src, p_mid2, p_mid1,
                                                   eidx, tdx, qdx,
                                                   score1, score2, score3,
                                                   off, eid, gmax, out1, out2, out3);

  // fused output GEMM + LN + PReLU
  gemm_ln<<<NN / 16, 256, 0, stream>>>(out1, out2, out3, x, flags, fp, outp);
}

// Round 3
// 1437.650 us; speedup vs baseline: 1.3130x; 1.3003x over previous
//
#include <hip/hip_runtime.h>

#define NN 50000
#define NE 400000
#define NT 300000
#define NQ 200000
#define DM 256
#define FIN 128
#define NRBF 40
#define BETA_RBF 40.0f
#define TOTALP 397569

// pass1 batch decomposition: 64 edges per batch
#define NB1 6250                 // NE/64 exactly
#define NB2 4688                 // ceil(NT/64), last batch has 32
#define NB3 3125                 // NQ/64 exactly
#define NBTOT (NB1 + NB2 + NB3)  // 14063

#define WSWZ_N (56 * 16 * 64 * 8)  // 458752 u16 swizzled-weight elements

typedef unsigned int u32;
typedef unsigned short u16;
typedef __attribute__((ext_vector_type(8))) short bf16x8;
typedef __attribute__((ext_vector_type(4))) float f32x4;

// ---- bf16 helpers ----
static __device__ __forceinline__ float bf2f(u16 h) {
  return __uint_as_float(((u32)h) << 16);
}
static __device__ __forceinline__ u16 f2bf(float f) {
  u32 u = __float_as_uint(f);
  u32 r = (u + 0x7FFFu + ((u >> 16) & 1u)) >> 16;  // RNE
  return (u16)r;
}
static __device__ __forceinline__ float4 ld4bf(const u16* p) {
  ushort4 v = *reinterpret_cast<const ushort4*>(p);
  return float4{bf2f(v.x), bf2f(v.y), bf2f(v.z), bf2f(v.w)};
}
static __device__ __forceinline__ float4 ld4f(const float* p) {
  return *reinterpret_cast<const float4*>(p);
}
static __device__ __forceinline__ float ldsc(const void* p, int isf, size_t i) {
  return isf ? ((const float*)p)[i] : bf2f(((const u16*)p)[i]);
}
static __device__ __forceinline__ float lk(float t) { return t >= 0.f ? t : 0.2f * t; }
static __device__ __forceinline__ u32 f2o(float f) {
  u32 u = __float_as_uint(f);
  return (u & 0x80000000u) ? ~u : (u | 0x80000000u);
}
static __device__ __forceinline__ float o2f(u32 e) {
  u32 b = (e & 0x80000000u) ? (e & 0x7fffffffu) : ~e;
  return __uint_as_float(b);
}

struct F3 { float x, y, z; };
static __device__ __forceinline__ F3 ldp(const float* pos, int i) {
  return F3{pos[3 * i], pos[3 * i + 1], pos[3 * i + 2]};
}
static __device__ __forceinline__ F3 sub3(F3 a, F3 b) { return F3{a.x - b.x, a.y - b.y, a.z - b.z}; }
static __device__ __forceinline__ float dot3(F3 a, F3 b) { return a.x * b.x + a.y * b.y + a.z * b.z; }
static __device__ __forceinline__ F3 cross3(F3 a, F3 b) {
  return F3{a.y * b.z - a.z * b.y, a.z * b.x - a.x * b.z, a.x * b.y - a.y * b.x};
}
static __device__ __forceinline__ float norm3(F3 v) { return sqrtf(dot3(v, v) + 1e-12f); }
static __device__ __forceinline__ float angle_at(F3 a, F3 m, F3 b) {
  F3 u = sub3(a, m), v = sub3(b, m);
  float c = dot3(u, v) / (norm3(u) * norm3(v) + 1e-12f);
  c = fminf(fmaxf(c, -1.f + 1e-7f), 1.f - 1e-7f);
  return acosf(c);
}
static __device__ __forceinline__ float dihedral_f(F3 p0, F3 p1, F3 p2, F3 p3) {
  F3 b1 = sub3(p1, p0), b2 = sub3(p2, p1), b3 = sub3(p3, p2);
  F3 n1 = cross3(b1, b2), n2 = cross3(b2, b3);
  float nb2 = norm3(b2) + 1e-12f;
  F3 b2n{b2.x / nb2, b2.y / nb2, b2.z / nb2};
  F3 m1 = cross3(n1, b2n);
  return atan2f(dot3(m1, n2), dot3(n1, n2) + 1e-12f);
}

// phase A: scalar RBF window + 8 coefficients for ONE edge (per lane).
static __device__ __forceinline__ int rbf_coef(float d, float* c) {
  int j = (int)floorf(d * 4.0f) - 3;
  j = (j < 0) ? 0 : ((j > NRBF - 8) ? (NRBF - 8) : j);
  float t0 = d - 0.25f * (float)j;
#pragma unroll
  for (int k = 0; k < 8; ++k) {
    float t = t0 - 0.25f * (float)k;
    c[k] = __expf(-BETA_RBF * t * t);
  }
  return j;
}

// phase B: dm += sum_k c_k * Wu[j+k][c4..c4+3]
static __device__ __forceinline__ float4 rbf_apply(const float* __restrict__ base,
                                                   float4 c0, float4 c1, float4 dm) {
  float4 w;
  w = ld4f(base + 0 * DM);
  dm.x = fmaf(c0.x, w.x, dm.x); dm.y = fmaf(c0.x, w.y, dm.y);
  dm.z = fmaf(c0.x, w.z, dm.z); dm.w = fmaf(c0.x, w.w, dm.w);
  w = ld4f(base + 1 * DM);
  dm.x = fmaf(c0.y, w.x, dm.x); dm.y = fmaf(c0.y, w.y, dm.y);
  dm.z = fmaf(c0.y, w.z, dm.z); dm.w = fmaf(c0.y, w.w, dm.w);
  w = ld4f(base + 2 * DM);
  dm.x = fmaf(c0.z, w.x, dm.x); dm.y = fmaf(c0.z, w.y, dm.y);
  dm.z = fmaf(c0.z, w.z, dm.z); dm.w = fmaf(c0.z, w.w, dm.w);
  w = ld4f(base + 3 * DM);
  dm.x = fmaf(c0.w, w.x, dm.x); dm.y = fmaf(c0.w, w.y, dm.y);
  dm.z = fmaf(c0.w, w.z, dm.z); dm.w = fmaf(c0.w, w.w, dm.w);
  w = ld4f(base + 4 * DM);
  dm.x = fmaf(c1.x, w.x, dm.x); dm.y = fmaf(c1.x, w.y, dm.y);
  dm.z = fmaf(c1.x, w.z, dm.z); dm.w = fmaf(c1.x, w.w, dm.w);
  w = ld4f(base + 5 * DM);
  dm.x = fmaf(c1.y, w.x, dm.x); dm.y = fmaf(c1.y, w.y, dm.y);
  dm.z = fmaf(c1.y, w.z, dm.z); dm.w = fmaf(c1.y, w.w, dm.w);
  w = ld4f(base + 6 * DM);
  dm.x = fmaf(c1.z, w.x, dm.x); dm.y = fmaf(c1.z, w.y, dm.y);
  dm.z = fmaf(c1.z, w.z, dm.z); dm.w = fmaf(c1.z, w.w, dm.w);
  w = ld4f(base + 7 * DM);
  dm.x = fmaf(c1.w, w.x, dm.x); dm.y = fmaf(c1.w, w.y, dm.y);
  dm.z = fmaf(c1.w, w.z, dm.z); dm.w = fmaf(c1.w, w.w, dm.w);
  return dm;
}

static __device__ __forceinline__ ushort4 g512(const u16* p, int idx, int c4) {
  return *reinterpret_cast<const ushort4*>(p + (size_t)(u32)idx * DM + c4);
}
static __device__ __forceinline__ float4 cvt4(ushort4 v) {
  return float4{bf2f(v.x), bf2f(v.y), bf2f(v.z), bf2f(v.w)};
}

// param staging table: 30 tensors, cumulative offsets
__device__ const int g_off[31] = {
  0, 32768, 65536, 98304, 131072, 131584, 131840, 142080, 142336, 152576,
  152832, 163072, 163328, 163840, 164096, 165632, 165888, 231424, 231680,
  297216, 297472, 363008, 363264, 363520, 363776, 364032, 396800, 397056,
  397312, 397568, 397569};
struct PtrTab { const void* p[30]; };

// ---- init ----
__global__ __launch_bounds__(256) void init_detect(const u32* __restrict__ aw,
                                                   const u32* __restrict__ lng,
                                                   u32* __restrict__ gmax,
                                                   int* __restrict__ flags) {
  __shared__ int s_int, s_f32, s_bf;
  if (threadIdx.x == 0) { s_int = 1; s_f32 = 1; s_bf = 1; }
  __syncthreads();
  int li = 1, lf = 1, lb = 1;
  for (int i = threadIdx.x; i < 1024; i += 256) {
    u32 w = aw[i];
    if (w > 1u) li = 0;
    if (w != 0u && w != 0x3F800000u) lf = 0;
    u32 h0 = w & 0xFFFFu, h1 = w >> 16;
    if ((h0 != 0u && h0 != 0x3F80u) || (h1 != 0u && h1 != 0x3F80u)) lb = 0;
  }
  if (!li) atomicAnd(&s_int, 0);
  if (!lf) atomicAnd(&s_f32, 0);
  if (!lb) atomicAnd(&s_bf, 0);
  __syncthreads();
  if (threadIdx.x == 0) {
    flags[0] = s_int ? 0 : (s_f32 ? 2 : (s_bf ? 3 : 1));
    flags[1] = ((lng[0] & 0xFFFFu) == 0x3F80u) ? 0 : 1;  // 1 = fp32 inputs
    gmax[0] = f2o(-INFINITY);
    gmax[1] = f2o(-INFINITY);
    gmax[2] = f2o(-INFINITY);
    gmax[3] = 0u;  // pass1 work-steal counter
  }
}

__global__ __launch_bounds__(256) void convert_params(PtrTab tab,
                                                      const int* __restrict__ flags,
                                                      float* __restrict__ dst) {
  const int isf = flags[1];
  for (int i = blockIdx.x * blockDim.x + threadIdx.x; i < TOTALP;
       i += gridDim.x * blockDim.x) {
    int t = 0;
    while (i >= g_off[t + 1]) ++t;
    dst[i] = ldsc(tab.p[t], isf, i - g_off[t]);
  }
}
__global__ __launch_bounds__(256) void convert_pos(const void* __restrict__ pos,
                                                   const int* __restrict__ flags,
                                                   float* __restrict__ posf) {
  const int isf = flags[1];
  for (int i = blockIdx.x * blockDim.x + threadIdx.x; i < NN * 3;
       i += gridDim.x * blockDim.x)
    posf[i] = ldsc(pos, isf, i);
}

static __device__ __forceinline__ int read_eattr(const void* p, int flag, int e) {
  if (flag == 1) return ((const unsigned char*)p)[e];
  if (flag == 2) return (((const float*)p)[e] != 0.f);
  if (flag == 3) return (((const u16*)p)[e] != 0);
  return ((const int*)p)[e];
}

// ---- weight swizzle for MFMA B-fragments ----
// 56 k-step slots: 0..23 = [W1|W2|W3] hi, 24..47 = same lo,
// 48..51 = Wr hi, 52..55 = Wr lo. Element (s,nb,lane,j):
// value = Wpart[K(s, 8*(lane>>4)+j)][nb*16 + (lane&15)].
__global__ __launch_bounds__(256) void swizzle_w(const float* __restrict__ fp,
                                                 u16* __restrict__ wswz) {
  int idx = blockIdx.x * 256 + threadIdx.x;
  if (idx >= WSWZ_N) return;
  int jj = idx & 7;
  int lane = (idx >> 3) & 63;
  int nb = (idx >> 9) & 15;
  int s = idx >> 13;
  int kl = (lane >> 4) * 8 + jj;
  int col = nb * 16 + (lane & 15);
  float w;
  int lo;
  if (s < 48) {
    int sr = (s < 24) ? s : (s - 24);
    lo = (s >= 24);
    int K = sr * 32 + kl;
    int base = (K < 256) ? 165888 : ((K < 512) ? 231680 : 297472);
    w = fp[base + (K & 255) * 256 + col];
  } else {
    int sr = (s < 52) ? (s - 48) : (s - 52);
    lo = (s >= 52);
    int K = sr * 32 + kl;
    w = fp[364032 + K * 256 + col];
  }
  u16 hi = f2bf(w);
  wswz[idx] = lo ? f2bf(w - bf2f(hi)) : hi;
}

// ---- x hi/lo split into Xs[NN][256] (cols 0..127 hi, 128..255 lo) ----
__global__ __launch_bounds__(256) void xsplit(const void* __restrict__ x,
                                              const int* __restrict__ flags,
                                              u16* __restrict__ Xs) {
  const int isf = flags[1];
  for (int i = blockIdx.x * blockDim.x + threadIdx.x; i < NN * FIN;
       i += gridDim.x * blockDim.x) {
    int n = i >> 7, k = i & 127;
    float v = ldsc(x, isf, i);
    u16 hi = f2bf(v);
    Xs[(size_t)n * 256 + k] = hi;
    Xs[(size_t)n * 256 + 128 + k] = f2bf(v - bf2f(hi));
  }
}

// ---- fused 4-way projection ----
__global__ __launch_bounds__(256) void proj4_kernel(
    const void* __restrict__ x, const int* __restrict__ flags,
    const float* __restrict__ W0, const float* __restrict__ W1,
    const float* __restrict__ W2, const float* __restrict__ W3,
    u16* __restrict__ o0, u16* __restrict__ o1,
    u16* __restrict__ o2, u16* __restrict__ o3) {
  __shared__ float sx[16 * FIN];
  const int c = threadIdx.x;
  const int n0 = blockIdx.x * 16;
  const int isf = flags[1];
#pragma unroll
  for (int i = 0; i < 8; ++i) {
    int l = i * 256 + c;
    sx[l] = ldsc(x, isf, (size_t)n0 * FIN + l);
  }
  __syncthreads();
  float dv = expf(-logf(10000.f) * (float)(c & ~1) / 256.f);
  float p0 = (c & 1) ? cosf(0.f * dv) : sinf(0.f * dv);
  float p1 = (c & 1) ? cosf(1.f * dv) : sinf(1.f * dv);
  float p2 = (c & 1) ? cosf(2.f * dv) : sinf(2.f * dv);
  float p3 = (c & 1) ? cosf(3.f * dv) : sinf(3.f * dv);
  float a0[16], a1[16], a2[16], a3[16];
#pragma unroll
  for (int r = 0; r < 16; ++r) { a0[r] = p0; a1[r] = p1; a2[r] = p2; a3[r] = p3; }
  for (int k = 0; k < FIN; ++k) {
    float w0 = W0[k * DM + c], w1 = W1[k * DM + c];
    float w2 = W2[k * DM + c], w3 = W3[k * DM + c];
#pragma unroll
    for (int r = 0; r < 16; ++r) {
      float xr = sx[r * FIN + k];
      a0[r] = fmaf(xr, w0, a0[r]);
      a1[r] = fmaf(xr, w1, a1[r]);
      a2[r] = fmaf(xr, w2, a2[r]);
      a3[r] = fmaf(xr, w3, a3[r]);
    }
  }
#pragma unroll
  for (int r = 0; r < 16; ++r) {
    size_t off = (size_t)(n0 + r) * DM + c;
    o0[off] = f2bf(a0[r]); o1[off] = f2bf(a1[r]);
    o2[off] = f2bf(a2[r]); o3[off] = f2bf(a3[r]);
  }
}

// ---- fused CSR build over the 3 hops ----
__global__ __launch_bounds__(256) void hist_all(const int* __restrict__ ed,
                                                const int* __restrict__ td,
                                                const int* __restrict__ qd,
                                                int* __restrict__ deg) {
  const int M = NE + NT + NQ;
  for (int i = blockIdx.x * blockDim.x + threadIdx.x; i < M; i += gridDim.x * blockDim.x) {
    if (i < NE) atomicAdd(&deg[ed[i]], 1);
    else if (i < NE + NT) atomicAdd(&deg[NN + td[i - NE]], 1);
    else atomicAdd(&deg[2 * NN + qd[i - NE - NT]], 1);
  }
}
__global__ __launch_bounds__(1024) void scan_all(const int* __restrict__ degall,
                                                 int* __restrict__ offall,
                                                 int* __restrict__ curall) {
  __shared__ int part[1024];
  const int b = blockIdx.x;
  const int* deg = degall + (size_t)b * NN;
  int* off = offall + (size_t)b * (NN + 1);
  int* cur = curall + (size_t)b * NN;
  const int CH = (NN + 1023) / 1024;
  const int t = threadIdx.x;
  const int base = t * CH;
  int s = 0;
  for (int i = 0; i < CH; ++i) { int idx = base + i; if (idx < NN) s += deg[idx]; }
  part[t] = s;
  __syncthreads();
  for (int d = 1; d < 1024; d <<= 1) {
    int v = (t >= d) ? part[t - d] : 0;
    __syncthreads();
    part[t] += v;
    __syncthreads();
  }
  int run = (t == 0) ? 0 : part[t - 1];
  for (int i = 0; i < CH; ++i) {
    int idx = base + i;
    if (idx < NN) { off[idx] = run; cur[idx] = run; run += deg[idx]; }
  }
  if (t == 1023) off[NN] = run;
}
__global__ __launch_bounds__(256) void fill_all(const int* __restrict__ ed,
                                                const int* __restrict__ td,
                                                const int* __restrict__ qd,
                                                int* __restrict__ cur,
                                                int* __restrict__ eid) {
  const int M = NE + NT + NQ;
  for (int i = blockIdx.x * blockDim.x + threadIdx.x; i < M; i += gridDim.x * blockDim.x) {
    if (i < NE) {
      int p = atomicAdd(&cur[ed[i]], 1);
      eid[p] = i;
    } else if (i < NE + NT) {
      int il = i - NE;
      int p = atomicAdd(&cur[NN + td[il]], 1);
      eid[NE + p] = il;
    } else {
      int il = i - NE - NT;
      int p = atomicAdd(&cur[2 * NN + qd[il]], 1);
      eid[NE + NT + p] = il;
    }
  }
}

// ---- fused pass1 (phase-split, work-stealing) ----
__global__ __launch_bounds__(256, 4) void pass1_all(
    const float* __restrict__ pos,
    const int* __restrict__ eidx, const int* __restrict__ tdx, const int* __restrict__ qdx,
    const void* __restrict__ eattr, const int* __restrict__ flags,
    const u16* __restrict__ p_src, const u16* __restrict__ p_mid2,
    const u16* __restrict__ p_mid1, const u16* __restrict__ p_dst,
    const float* __restrict__ fp,
    float* __restrict__ score1, float* __restrict__ score2, float* __restrict__ score3,
    u32* __restrict__ gmax) {
  __shared__ __align__(16) float slds[4][64 * 20];
  const int lane = threadIdx.x & 63;
  float* sw = slds[threadIdx.x >> 6];
  const int c4 = lane * 4;
  const int flag = flags[0];

  for (int it = 0; it <= NBTOT; ++it) {
    u32 bl = 0;
    if (lane == 0) bl = atomicAdd(gmax + 3, 1u);
    u32 b0 = (u32)__builtin_amdgcn_readfirstlane((int)bl);
    if (b0 >= NBTOT) break;

    if (b0 < NB1) {
      // ================= hop 1 =================
      const int e0 = (int)b0 * 64;
      {  // phase A
        int e = e0 + lane;
        int es = eidx[e], ed = eidx[NE + e];
        int ea = read_eattr(eattr, flag, e);
        F3 Ps = ldp(pos, es), Pd = ldp(pos, ed);
        float d1 = norm3(sub3(Ps, Pd));
        float c[8]; int j = 0; float f0, f1;
        if (ea) {
          float dc = fminf(fmaxf(d1, 0.05f), 10.f);
          j = rbf_coef(dc, c);
          f0 = 0.f; f1 = 0.f;
        } else {
#pragma unroll
          for (int k = 0; k < 8; ++k) c[k] = 0.f;
          f0 = d1; f1 = d1 * d1;
        }
        float* sp = sw + lane * 20;
        *reinterpret_cast<int4*>(sp) = int4{es, ed, ea, j};
        *reinterpret_cast<float4*>(sp + 4) = float4{c[0], c[1], c[2], c[3]};
        *reinterpret_cast<float4*>(sp + 8) = float4{c[4], c[5], c[6], c[7]};
        *reinterpret_cast<float4*>(sp + 12) = float4{f0, f1, 0.f, 0.f};
      }
      // phase B
      const float* Wu = fp + 131840;
      float4 av = ld4f(fp + 363264 + c4);
      float4 bbv = ld4f(fp + 131584 + c4), buv = ld4f(fp + 142080 + c4);
      float4 bsum{bbv.x + buv.x, bbv.y + buv.y, bbv.z + buv.z, bbv.w + buv.w};
      float4 wb0 = ld4f(fp + 131072 + c4), wb1 = ld4f(fp + 131072 + DM + c4);
      float rmax = -INFINITY;
      int4 I = *reinterpret_cast<const int4*>(sw);
      ushort4 gm = g512(p_mid1, I.x, c4);
      ushort4 gd = g512(p_dst, I.y, c4);
#pragma unroll 1
      for (int e = 0; e < 64; ++e) {
        int4 In{0, 0, 0, 0};
        ushort4 gmn{0, 0, 0, 0}, gdn{0, 0, 0, 0};
        if (e + 1 < 64) {
          In = *reinterpret_cast<const int4*>(sw + (e + 1) * 20);
          gmn = g512(p_mid1, In.x, c4);
          gdn = g512(p_dst, In.y, c4);
        }
        const float* sp = sw + e * 20;
        float4 dm = bsum;
        if (I.z) {
          float4 cc0 = *reinterpret_cast<const float4*>(sp + 4);
          float4 cc1 = *reinterpret_cast<const float4*>(sp + 8);
          dm = rbf_apply(Wu + I.w * DM + c4, cc0, cc1, dm);
        } else {
          float4 f = *reinterpret_cast<const float4*>(sp + 12);
          dm.x = fmaf(f.x, wb0.x, fmaf(f.y, wb1.x, dm.x));
          dm.y = fmaf(f.x, wb0.y, fmaf(f.y, wb1.y, dm.y));
          dm.z = fmaf(f.x, wb0.z, fmaf(f.y, wb1.z, dm.z));
          dm.w = fmaf(f.x, wb0.w, fmaf(f.y, wb1.w, dm.w));
        }
        float4 m = cvt4(gm), dd = cvt4(gd);
        float s0 = lk((m.x + dd.x) * dm.x);
        float s1 = lk((m.y + dd.y) * dm.y);
        float s2 = lk((m.z + dd.z) * dm.z);
        float s3 = lk((m.w + dd.w) * dm.w);
        float part = av.x * s0 + av.y * s1 + av.z * s2 + av.w * s3;
        part += __shfl_xor(part, 1, 64);
        part += __shfl_xor(part, 2, 64);
        part += __shfl_xor(part, 4, 64);
        if ((lane & 7) == 0) score1[(size_t)(e0 + e) * 8 + (lane >> 3)] = part;
        rmax = fmaxf(rmax, part);
        I = In; gm = gmn; gd = gdn;
      }
      for (int m = 32; m; m >>= 1) rmax = fmaxf(rmax, __shfl_xor(rmax, m, 64));
      if (lane == 0) atomicMax(gmax + 0, f2o(rmax));
    } else if (b0 < NB1 + NB2) {
      // ================= hop 2 =================
      const int t0 = ((int)b0 - NB1) * 64;
      const int cnt = (NT - t0 < 64) ? (NT - t0) : 64;
      if (lane < cnt) {  // phase A
        int t = t0 + lane;
        int ts = tdx[t], tm = tdx[NT + t], td = tdx[2 * NT + t];
        F3 Ps = ldp(pos, ts), Pm = ldp(pos, tm), Pd = ldp(pos, td);
        float d2 = fminf(fmaxf(norm3(sub3(Ps, Pd)), 0.05f), 10.f);
        float c[8];
        int j = rbf_coef(d2, c);
        float ang = angle_at(Ps, Pm, Pd);
        float* sp = sw + lane * 20;
        *reinterpret_cast<int4*>(sp) = int4{ts, tm, td, j};
        *reinterpret_cast<float4*>(sp + 4) = float4{c[0], c[1], c[2], c[3]};
        *reinterpret_cast<float4*>(sp + 8) = float4{c[4], c[5], c[6], c[7]};
        *reinterpret_cast<float4*>(sp + 12) = float4{ang, ang * ang, 0.f, 0.f};
      }
      // phase B
      const float* Wu1 = fp + 142336;
      float4 av = ld4f(fp + 363520 + c4);
      float4 b1v = ld4f(fp + 152576 + c4), b2v = ld4f(fp + 163840 + c4);
      float4 bsum{b1v.x + b2v.x, b1v.y + b2v.y, b1v.z + b2v.z, b1v.w + b2v.w};
      float4 wa0 = ld4f(fp + 163328 + c4), wa1 = ld4f(fp + 163328 + DM + c4);
      float rmax = -INFINITY;
      int4 I = *reinterpret_cast<const int4*>(sw);
      ushort4 g0 = g512(p_mid2, I.x, c4);
      ushort4 g1 = g512(p_mid1, I.y, c4);
      ushort4 g2 = g512(p_dst, I.z, c4);
#pragma unroll 1
      for (int e = 0; e < cnt; ++e) {
        int4 In{0, 0, 0, 0};
        ushort4 g0n{0, 0, 0, 0}, g1n{0, 0, 0, 0}, g2n{0, 0, 0, 0};
        if (e + 1 < cnt) {
          In = *reinterpret_cast<const int4*>(sw + (e + 1) * 20);
          g0n = g512(p_mid2, In.x, c4);
          g1n = g512(p_mid1, In.y, c4);
          g2n = g512(p_dst, In.z, c4);
        }
        const float* sp = sw + e * 20;
        float4 cc0 = *reinterpret_cast<const float4*>(sp + 4);
        float4 cc1 = *reinterpret_cast<const float4*>(sp + 8);
        float4 f = *reinterpret_cast<const float4*>(sp + 12);
        float4 dm;
        dm.x = fmaf(f.x, wa0.x, fmaf(f.y, wa1.x, bsum.x));
        dm.y = fmaf(f.x, wa0.y, fmaf(f.y, wa1.y, bsum.y));
        dm.z = fmaf(f.x, wa0.z, fmaf(f.y, wa1.z, bsum.z));
        dm.w = fmaf(f.x, wa0.w, fmaf(f.y, wa1.w, bsum.w));
        dm = rbf_apply(Wu1 + I.w * DM + c4, cc0, cc1, dm);
        float4 v0 = cvt4(g0), v2 = cvt4(g1), v1 = cvt4(g2);
        float s0 = lk((v0.x + v1.x + v2.x) * dm.x);
        float s1 = lk((v0.y + v1.y + v2.y) * dm.y);
        float s2 = lk((v0.z + v1.z + v2.z) * dm.z);
        float s3 = lk((v0.w + v1.w + v2.w) * dm.w);
        float part = av.x * s0 + av.y * s1 + av.z * s2 + av.w * s3;
        part += __shfl_xor(part, 1, 64);
        part += __shfl_xor(part, 2, 64);
        part += __shfl_xor(part, 4, 64);
        if ((lane & 7) == 0) score2[(size_t)(t0 + e) * 8 + (lane >> 3)] = part;
        rmax = fmaxf(rmax, part);
        I = In; g0 = g0n; g1 = g1n; g2 = g2n;
      }
      for (int m = 32; m; m >>= 1) rmax = fmaxf(rmax, __shfl_xor(rmax, m, 64));
      if (lane == 0) atomicMax(gmax + 1, f2o(rmax));
    } else {
      // ================= hop 3 =================
      const int q0 = ((int)b0 - NB1 - NB2) * 64;
      {  // phase A
        int q = q0 + lane;
        int qs = qdx[q], q2 = qdx[NQ + q], q1 = qdx[2 * NQ + q], qd = qdx[3 * NQ + q];
        F3 P0 = ldp(pos, qs), P1 = ldp(pos, q2), P2 = ldp(pos, q1), P3 = ldp(pos, qd);
        float d3 = fminf(fmaxf(norm3(sub3(P0, P3)), 0.05f), 10.f);
        float c[8];
        int j = rbf_coef(d3, c);
        float a1f = angle_at(P0, P1, P2);
        float a2f = angle_at(P1, P2, P3);
        float dh = dihedral_f(P0, P1, P2, P3);
        float* sp = sw + lane * 20;
        *reinterpret_cast<int4*>(sp) = int4{qs, q2, q1, qd};
        *reinterpret_cast<float4*>(sp + 4) = float4{c[0], c[1], c[2], c[3]};
        *reinterpret_cast<float4*>(sp + 8) = float4{c[4], c[5], c[6], c[7]};
        *reinterpret_cast<float4*>(sp + 12) = float4{a1f, a1f * a1f, a2f, a2f * a2f};
        *reinterpret_cast<float4*>(sp + 16) = float4{dh, dh * dh, __int_as_float(j), 0.f};
      }
      // phase B
      const float* Wu2 = fp + 152832;
      const float* Wd = fp + 164096;
      float4 av = ld4f(fp + 363776 + c4);
      float4 b1v = ld4f(fp + 163072 + c4), b2v = ld4f(fp + 165632 + c4);
      float4 bsum{b1v.x + b2v.x, b1v.y + b2v.y, b1v.z + b2v.z, b1v.w + b2v.w};
      float4 wd0 = ld4f(Wd + c4), wd1 = ld4f(Wd + DM + c4), wd2 = ld4f(Wd + 2 * DM + c4);
      float4 wd3 = ld4f(Wd + 3 * DM + c4), wd4 = ld4f(Wd + 4 * DM + c4), wd5 = ld4f(Wd + 5 * DM + c4);
      float rmax = -INFINITY;
      int4 I = *reinterpret_cast<const int4*>(sw);
      float4 fb = *reinterpret_cast<const float4*>(sw + 16);
      ushort4 g0 = g512(p_src, I.x, c4), g1 = g512(p_mid2, I.y, c4);
      ushort4 g2 = g512(p_mid1, I.z, c4), g3 = g512(p_dst, I.w, c4);
#pragma unroll 1
      for (int e = 0; e < 64; ++e) {
        int4 In{0, 0, 0, 0};
        float4 fbn{0.f, 0.f, 0.f, 0.f};
        ushort4 g0n{0, 0, 0, 0}, g1n{0, 0, 0, 0}, g2n{0, 0, 0, 0}, g3n{0, 0, 0, 0};
        if (e + 1 < 64) {
          In = *reinterpret_cast<const int4*>(sw + (e + 1) * 20);
          fbn = *reinterpret_cast<const float4*>(sw + (e + 1) * 20 + 16);
          g0n = g512(p_src, In.x, c4);
          g1n = g512(p_mid2, In.y, c4);
          g2n = g512(p_mid1, In.z, c4);
          g3n = g512(p_dst, In.w, c4);
        }
        const float* sp = sw + e * 20;
        float4 cc0 = *reinterpret_cast<const float4*>(sp + 4);
        float4 cc1 = *reinterpret_cast<const float4*>(sp + 8);
        float4 f = *reinterpret_cast<const float4*>(sp + 12);
        int j = __float_as_int(fb.z);
        float4 dm;
        dm.x = bsum.x + f.x * wd0.x + f.y * wd1.x + f.z * wd2.x + f.w * wd3.x + fb.x * wd4.x + fb.y * wd5.x;
        dm.y = bsum.y + f.x * wd0.y + f.y * wd1.y + f.z * wd2.y + f.w * wd3.y + fb.x * wd4.y + fb.y * wd5.y;
        dm.z = bsum.z + f.x * wd0.z + f.y * wd1.z + f.z * wd2.z + f.w * wd3.z + fb.x * wd4.z + fb.y * wd5.z;
        dm.w = bsum.w + f.x * wd0.w + f.y * wd1.w + f.z * wd2.w + f.w * wd3.w + fb.x * wd4.w + fb.y * wd5.w;
        dm = rbf_apply(Wu2 + j * DM + c4, cc0, cc1, dm);
        float4 v0 = cvt4(g0), v1 = cvt4(g1), v2 = cvt4(g2), v3 = cvt4(g3);
        float s0 = lk((v0.x + v1.x + v2.x + v3.x) * dm.x);
        float s1 = lk((v0.y + v1.y + v2.y + v3.y) * dm.y);
        float s2 = lk((v0.z + v1.z + v2.z + v3.z) * dm.z);
        float s3 = lk((v0.w + v1.w + v2.w + v3.w) * dm.w);
        float part = av.x * s0 + av.y * s1 + av.z * s2 + av.w * s3;
        part += __shfl_xor(part, 1, 64);
        part += __shfl_xor(part, 2, 64);
        part += __shfl_xor(part, 4, 64);
        if ((lane & 7) == 0) score3[(size_t)(q0 + e) * 8 + (lane >> 3)] = part;
        rmax = fmaxf(rmax, part);
        I = In; fb = fbn; g0 = g0n; g1 = g1n; g2 = g2n; g3 = g3n;
      }
      for (int m = 32; m; m >>= 1) rmax = fmaxf(rmax, __shfl_xor(rmax, m, 64));
      if (lane == 0) atomicMax(gmax + 2, f2o(rmax));
    }
  }
}

// ---- fused gather: writes bf16 into unified A-buffer [NN][768] ----
__global__ __launch_bounds__(256) void gather_all(
    const u16* __restrict__ p_src, const u16* __restrict__ p_mid2,
    const u16* __restrict__ p_mid1,
    const int* __restrict__ eidx, const int* __restrict__ tdx, const int* __restrict__ qdx,
    const float* __restrict__ score1, const float* __restrict__ score2,
    const float* __restrict__ score3,
    const int* __restrict__ offall, const int* __restrict__ eidall,
    const u32* __restrict__ gmax,
    u16* __restrict__ Abuf) {
  const int W = (blockIdx.x * blockDim.x + threadIdx.x) >> 6;
  if (W >= 3 * NN) return;
  const int lane = threadIdx.x & 63;
  const int h = lane >> 3;
  const int c4 = lane * 4;
  const int hop = (W < NN) ? 0 : ((W < 2 * NN) ? 1 : 2);
  const int node = W - hop * NN;
  const int* offp = offall + (size_t)hop * (NN + 1);
  const int* eidp = eidall + ((hop == 0) ? 0 : ((hop == 1) ? NE : (NE + NT)));
  const int* gsrc = (hop == 0) ? eidx : ((hop == 1) ? tdx : qdx);
  const float* scr = (hop == 0) ? score1 : ((hop == 1) ? score2 : score3);
  const u16* sv = (hop == 0) ? p_mid1 : ((hop == 1) ? p_mid2 : p_src);
  const float g = o2f(gmax[hop]);
  const int s0 = offp[node], s1 = offp[node + 1];
  float4 vacc{0.f, 0.f, 0.f, 0.f};
  float wsum = 0.f;
  for (int j = s0; j < s1; ++j) {
    int e = eidp[j];
    int s = gsrc[e];
    float ev = expf(scr[(size_t)e * 8 + h] - g);
    wsum += ev;
    float4 v = ld4bf(sv + (size_t)s * DM + c4);
    vacc.x = fmaf(ev, v.x, vacc.x);
    vacc.y = fmaf(ev, v.y, vacc.y);
    vacc.z = fmaf(ev, v.z, vacc.z);
    vacc.w = fmaf(ev, v.w, vacc.w);
  }
  float inv = 1.f / (wsum + 1e-16f);
  ushort4 o;
  o.x = f2bf(vacc.x * inv);
  o.y = f2bf(vacc.y * inv);
  o.z = f2bf(vacc.z * inv);
  o.w = f2bf(vacc.w * inv);
  *reinterpret_cast<ushort4*>(Abuf + (size_t)node * 768 + hop * 256 + c4) = o;
}

// ---- MFMA output GEMM + LayerNorm + PReLU ----
// Block = 32 rows x 256 cols; 4 waves, wave w owns cols [w*64, w*64+64).
// Per wave: 2 M-frags x 4 N-frags of 16x16, K-eff = 1920 via hi/lo weight split.
// A: Abuf [NN][768] bf16 (exact); X: Xs [NN][256] = xhi|xlo.
// a-frag: row = lane&15, k = 8*(lane>>4)+j; b-frag pre-swizzled by swizzle_w.
// C/D: col = lane&15, row = 4*(lane>>4)+reg (m89-verified).
__global__ __launch_bounds__(256) void gemm_mfma_ln(
    const u16* __restrict__ Abuf, const u16* __restrict__ Xs,
    const u16* __restrict__ wswz, const float* __restrict__ fp,
    float* __restrict__ outp) {
  __shared__ float sS[4][32], sQ[4][32], sMu[32], sRs[32];
  const int tid = threadIdx.x;
  const int wid = tid >> 6, lane = tid & 63;
  const int g = lane >> 4, l15 = lane & 15;
  const int m0 = blockIdx.x * 32;
  const int cb = wid * 64;

  f32x4 acc[2][4];
#pragma unroll
  for (int nf = 0; nf < 4; ++nf) {
    int c = cb + nf * 16 + l15;
    float bs = fp[231424 + c] + fp[297216 + c] + fp[363008 + c] + fp[396800 + c];
    acc[0][nf] = f32x4{bs, bs, bs, bs};
    acc[1][nf] = f32x4{bs, bs, bs, bs};
  }
  int rr0 = m0 + l15; if (rr0 > NN - 1) rr0 = NN - 1;
  int rr1 = m0 + 16 + l15; if (rr1 > NN - 1) rr1 = NN - 1;
  const u16* a0p = Abuf + (size_t)rr0 * 768 + g * 8;
  const u16* a1p = Abuf + (size_t)rr1 * 768 + g * 8;
  const u16* x0p = Xs + (size_t)rr0 * 256 + g * 8;
  const u16* x1p = Xs + (size_t)rr1 * 256 + g * 8;
  const u16* wb = wswz + (size_t)(wid * 4 * 64 + lane) * 8;  // + s*8192 + nf*512

  // main: K = 768 over [A1|A2|A3], hi (slot ks) + lo (slot ks+24)
#pragma unroll 2
  for (int ks = 0; ks < 24; ++ks) {
    bf16x8 a0 = *reinterpret_cast<const bf16x8*>(a0p + ks * 32);
    bf16x8 a1 = *reinterpret_cast<const bf16x8*>(a1p + ks * 32);
#pragma unroll
    for (int nf = 0; nf < 4; ++nf) {
      bf16x8 bh = *reinterpret_cast<const bf16x8*>(wb + (size_t)ks * 8192 + nf * 512);
      bf16x8 bl = *reinterpret_cast<const bf16x8*>(wb + (size_t)(ks + 24) * 8192 + nf * 512);
      acc[0][nf] = __builtin_amdgcn_mfma_f32_16x16x32_bf16(a0, bh, acc[0][nf], 0, 0, 0);
      acc[1][nf] = __builtin_amdgcn_mfma_f32_16x16x32_bf16(a1, bh, acc[1][nf], 0, 0, 0);
      acc[0][nf] = __builtin_amdgcn_mfma_f32_16x16x32_bf16(a0, bl, acc[0][nf], 0, 0, 0);
      acc[1][nf] = __builtin_amdgcn_mfma_f32_16x16x32_bf16(a1, bl, acc[1][nf], 0, 0, 0);
    }
  }
  // x segment: xhi@Wrhi + xhi@Wrlo + xlo@Wrhi
#pragma unroll
  for (int ks = 0; ks < 4; ++ks) {
    bf16x8 xh0 = *reinterpret_cast<const bf16x8*>(x0p + ks * 32);
    bf16x8 xh1 = *reinterpret_cast<const bf16x8*>(x1p + ks * 32);
    bf16x8 xl0 = *reinterpret_cast<const bf16x8*>(x0p + 128 + ks * 32);
    bf16x8 xl1 = *reinterpret_cast<const bf16x8*>(x1p + 128 + ks * 32);
#pragma unroll
    for (int nf = 0; nf < 4; ++nf) {
      bf16x8 bh = *reinterpret_cast<const bf16x8*>(wb + (size_t)(48 + ks) * 8192 + nf * 512);
      bf16x8 bl = *reinterpret_cast<const bf16x8*>(wb + (size_t)(52 + ks) * 8192 + nf * 512);
      acc[0][nf] = __builtin_amdgcn_mfma_f32_16x16x32_bf16(xh0, bh, acc[0][nf], 0, 0, 0);
      acc[1][nf] = __builtin_amdgcn_mfma_f32_16x16x32_bf16(xh1, bh, acc[1][nf], 0, 0, 0);
      acc[0][nf] = __builtin_amdgcn_mfma_f32_16x16x32_bf16(xh0, bl, acc[0][nf], 0, 0, 0);
      acc[1][nf] = __builtin_amdgcn_mfma_f32_16x16x32_bf16(xh1, bl, acc[1][nf], 0, 0, 0);
      acc[0][nf] = __builtin_amdgcn_mfma_f32_16x16x32_bf16(xl0, bh, acc[0][nf], 0, 0, 0);
      acc[1][nf] = __builtin_amdgcn_mfma_f32_16x16x32_bf16(xl1, bh, acc[1][nf], 0, 0, 0);
    }
  }

  // ---- LayerNorm stats: per row over 256 cols ----
#pragma unroll
  for (int mf = 0; mf < 2; ++mf) {
#pragma unroll
    for (int reg = 0; reg < 4; ++reg) {
      float sp = acc[mf][0][reg] + acc[mf][1][reg] + acc[mf][2][reg] + acc[mf][3][reg];
      float qp = acc[mf][0][reg] * acc[mf][0][reg] + acc[mf][1][reg] * acc[mf][1][reg] +
                 acc[mf][2][reg] * acc[mf][2][reg] + acc[mf][3][reg] * acc[mf][3][reg];
      for (int m = 8; m; m >>= 1) {
        sp += __shfl_xor(sp, m, 64);
        qp += __shfl_xor(qp, m, 64);
      }
      if (l15 == 0) {
        sS[wid][mf * 16 + g * 4 + reg] = sp;
        sQ[wid][mf * 16 + g * 4 + reg] = qp;
      }
    }
  }
  __syncthreads();
  if (tid < 32) {
    float S = sS[0][tid] + sS[1][tid] + sS[2][tid] + sS[3][tid];
    float Q = sQ[0][tid] + sQ[1][tid] + sQ[2][tid] + sQ[3][tid];
    float mu = S * (1.f / 256.f);
    float var = fmaxf(Q * (1.f / 256.f) - mu * mu, 0.f);
    sMu[tid] = mu;
    sRs[tid] = rsqrtf(var + 1e-5f);
  }
  __syncthreads();
  float pw = fp[397568];
#pragma unroll
  for (int nf = 0; nf < 4; ++nf) {
    int c = cb + nf * 16 + l15;
    float gc = fp[397056 + c], bc = fp[397312 + c];
#pragma unroll
    for (int mf = 0; mf < 2; ++mf) {
#pragma unroll
      for (int reg = 0; reg < 4; ++reg) {
        int rl = mf * 16 + g * 4 + reg;
        int row = m0 + rl;
        if (row < NN) {
          float y = (acc[mf][nf][reg] - sMu[rl]) * sRs[rl] * gc + bc;
          outp[(size_t)row * 256 + c] = (y >= 0.f) ? y : pw * y;
        }
      }
    }
  }
}

extern "C" void kernel_launch(void* const* d_in, const int* in_sizes, int n_in,
                              void* d_out, int out_size, void* d_ws, size_t ws_size,
                              hipStream_t stream) {
  const void* x = d_in[0];
  const void* pos = d_in[1];
  const int* eidx = (const int*)d_in[2];
  const int* tdx = (const int*)d_in[3];
  const int* qdx = (const int*)d_in[4];
  const void* eattr = d_in[5];
  float* outp = (float*)d_out;

  // workspace layout (~217 MB; proven safe <= ~221 MB)
  u16* p_src = (u16*)d_ws;
  u16* p_mid2 = p_src + (size_t)NN * DM;
  u16* p_mid1 = p_mid2 + (size_t)NN * DM;
  u16* p_dst = p_mid1 + (size_t)NN * DM;
  u16* Abuf = p_dst + (size_t)NN * DM;                // NN x 768 bf16 (A1|A2|A3)
  float* score1 = (float*)(Abuf + (size_t)NN * 768);  // NE*8
  float* score2 = score1 + (size_t)NE * 8;            // NT*8
  float* score3 = score2 + (size_t)NT * 8;            // NQ*8
  float* posf = score3 + (size_t)NQ * 8;              // NN*3
  float* fp = posf + (size_t)NN * 3;                  // staged params
  u16* wswz = (u16*)(fp + TOTALP + 3);                // 458752 u16 swizzled W
  int* deg = (int*)(fp + TOTALP + 3 + WSWZ_N / 2);    // 3*NN
  int* off = deg + 3 * NN;                            // 3*(NN+1)
  int* cur = off + 3 * (NN + 1);                      // 3*NN
  int* eid = cur + 3 * NN;                            // NE+NT+NQ
  u32* gmax = (u32*)(eid + NE + NT + NQ);
  int* flags = (int*)(gmax + 4);
  u16* Xs = p_dst;  // overlay: p_dst dead after pass1_all

  const float* W_src = fp + 0;
  const float* W_dst = fp + 32768;
  const float* W_mid1 = fp + 65536;
  const float* W_mid2 = fp + 98304;

  init_detect<<<1, 256, 0, stream>>>((const u32*)eattr, (const u32*)d_in[33], gmax, flags);

  PtrTab tab;
  for (int i = 0; i < 30; ++i) tab.p[i] = d_in[6 + i];
  convert_params<<<512, 256, 0, stream>>>(tab, flags, fp);
  convert_pos<<<587, 256, 0, stream>>>(pos, flags, posf);
  swizzle_w<<<WSWZ_N / 256, 256, 0, stream>>>(fp, wswz);

  proj4_kernel<<<NN / 16, 256, 0, stream>>>(x, flags, W_src, W_mid2, W_mid1, W_dst,
                                            p_src, p_mid2, p_mid1, p_dst);

  // CSR for all 3 hops
  hipMemsetAsync(deg, 0, (size_t)3 * NN * 4, stream);
  hist_all<<<1024, 256, 0, stream>>>(eidx + NE, tdx + 2 * NT, qdx + 3 * NQ, deg);
  scan_all<<<3, 1024, 0, stream>>>(deg, off, cur);
  fill_all<<<1024, 256, 0, stream>>>(eidx + NE, tdx + 2 * NT, qdx + 3 * NQ, cur, eid);

  // fused score pass (dynamic wave-level work stealing over 64-edge batches)
  pass1_all<<<2048, 256, 0, stream>>>(posf, eidx, tdx, qdx, eattr, flags,
                                      p_src, p_mid2, p_mid1, p_dst, fp,
                                      score1, score2, score3, gmax);

  // x hi/lo split into Xs (overwrites p_dst — dead after pass1)
  xsplit<<<2048, 256, 0, stream>>>(x, flags, Xs);

  // fused softmax-aggregate -> unified A buffer
  gather_all<<<(3 * NN + 3) / 4, 256, 0, stream>>>(p_src, p_mid2, p_mid1,
                                                   eidx, tdx, qdx,
                                                   score1, score2, score3,
                                                   off, eid, gmax, Abuf);

  // MFMA output GEMM + LN + PReLU
  gemm_mfma_ln<<<(NN + 31) / 32, 256, 0, stream>>>(Abuf, Xs, wswz, fp, outp);
}